// Round 14
// baseline (138.434 us; speedup 1.0000x reference)
//
#include <hip/hip_runtime.h>
#include <hip/hip_bf16.h>
#include <math.h>

#define NQ 6144
#define MR 6144
#define DIN 16
#define HID 256
#define INV_T 10.0f

typedef __attribute__((ext_vector_type(4))) float f32x4;
typedef __attribute__((ext_vector_type(8))) short bf16x8;

// Packed fragment-major operand layout (shorts):
//   pk[group][kc][l15][ksub*8 + j], group = row/16, kc = k/32, ksub = (k%32)/8
//   short offset = group*4096 + kc*512 + l15*32 + ksub*8
// A (group,kc) K-slice is a contiguous 1 KB -> ideal for global_load_lds
// (linear dest) and its ds_read frag pattern is bank-uniform (no swizzle).

static __device__ __forceinline__ unsigned short f2bf(float f) {
  __hip_bfloat16 h = __float2bfloat16(f);
  return __builtin_bit_cast(unsigned short, h);
}

// async global->LDS, 16 B per lane. LDS base must be wave-uniform.
static __device__ __forceinline__ void gload16(const void* g, void* l) {
  __builtin_amdgcn_global_load_lds(
      (const __attribute__((address_space(1))) unsigned int*)g,
      (__attribute__((address_space(3))) unsigned int*)l, 16, 0, 0);
}

// ---------------------------------------------------------------------------
// K0: prep — W2 -> bf16 (row-major), Wb -> bf16 transposed.
// ---------------------------------------------------------------------------
__global__ __launch_bounds__(256) void k_prep(
    const float* __restrict__ W2, const float* __restrict__ Wb,
    unsigned short* __restrict__ W2bf, unsigned short* __restrict__ Wbt)
{
  const int idx = blockIdx.x * 256 + threadIdx.x;  // = j*256 + c
  W2bf[idx] = f2bf(W2[idx]);
  const int j = idx >> 8, c = idx & 255;
  Wbt[(size_t)c * 256 + j] = f2bf(Wb[idx]);
}

// ---------------------------------------------------------------------------
// K1: compress (MFMA). 16 rows/block = one packed group, 256 thr (4 waves).
// ---------------------------------------------------------------------------
__global__ __launch_bounds__(256) void k_compress(
    const float* __restrict__ q, const float* __restrict__ ret,
    const float* __restrict__ W1, const float* __restrict__ b1,
    const unsigned short* __restrict__ W2bf, const float* __restrict__ b2,
    const unsigned short* __restrict__ Wbt,
    unsigned short* __restrict__ Apk, unsigned short* __restrict__ Bpk)
{
  const int tid = threadIdx.x;
  const bool is_q = blockIdx.x < (NQ / 16);
  const int grp = is_q ? blockIdx.x : blockIdx.x - NQ / 16;
  const int row0 = grp * 16;
  const float* x = is_q ? q : ret;

  __shared__ float xs[16][DIN];
  __shared__ __align__(16) unsigned short tb[16 * 256];
  __shared__ __align__(16) unsigned short hb[16 * 256];

  ((float*)xs)[tid] = x[(size_t)row0 * DIN + tid];
  __syncthreads();

  // ---- phase 1: gelu(x@W1^T + b1) -> tb (bf16, swizzled) ----
  {
    float w[DIN];
#pragma unroll
    for (int d = 0; d < DIN; ++d) w[d] = W1[tid * DIN + d];
    const float bb = b1[tid];
#pragma unroll
    for (int rr = 0; rr < 16; ++rr) {
      float a = bb;
#pragma unroll
      for (int d = 0; d < DIN; ++d) a += xs[rr][d] * w[d];
      a = 0.5f * a * (1.0f + erff(a * 0.70710678118654752f));
      tb[rr * 256 + (tid ^ ((rr & 7) << 3))] = f2bf(a);
    }
  }
  __syncthreads();

  const int wid = tid >> 6, lane = tid & 63;
  const int l15 = lane & 15;
  const int lk = (lane >> 4) * 8;

  // ---- phase 2: h = t @ W2^T + b2 -> hb ----
  {
    f32x4 acc[4];
#pragma unroll
    for (int ci = 0; ci < 4; ++ci) acc[ci] = (f32x4)0.0f;

    for (int kk = 0; kk < HID; kk += 32) {
      const bf16x8 a = *(const bf16x8*)&tb[l15 * 256 + ((kk + lk) ^ ((l15 & 7) << 3))];
#pragma unroll
      for (int ci = 0; ci < 4; ++ci) {
        const int bc = wid * 64 + ci * 16 + l15;
        const bf16x8 b = *(const bf16x8*)&W2bf[(size_t)bc * HID + kk + lk];
        acc[ci] = __builtin_amdgcn_mfma_f32_16x16x32_bf16(a, b, acc[ci], 0, 0, 0);
      }
    }

#pragma unroll
    for (int ci = 0; ci < 4; ++ci) {
      const int col = wid * 64 + ci * 16 + l15;
      const float bb2 = b2[col];
#pragma unroll
      for (int qq = 0; qq < 4; ++qq) {
        const int row = (lane >> 4) * 4 + qq;
        hb[row * 256 + (col ^ ((row & 7) << 3))] = f2bf(acc[ci][qq] + bb2);
      }
    }
  }
  __syncthreads();

  if (!is_q) {
#pragma unroll
    for (int i = 0; i < 2; ++i) {
      const int u = i * 256 + tid;
      const int kc = u >> 6, lr = (u >> 2) & 15, ks = u & 3;
      const int k = kc * 32 + ks * 8;
      const bf16x8 v = *(const bf16x8*)&hb[lr * 256 + (k ^ ((lr & 7) << 3))];
      *(bf16x8*)&Bpk[(size_t)grp * 4096 + (size_t)u * 8] = v;
    }
    return;
  }

  // ---- phase 3 (q only): g = h @ Wb ----
  {
    f32x4 acc[4];
#pragma unroll
    for (int ci = 0; ci < 4; ++ci) acc[ci] = (f32x4)0.0f;

    for (int kk = 0; kk < HID; kk += 32) {
      const bf16x8 a = *(const bf16x8*)&hb[l15 * 256 + ((kk + lk) ^ ((l15 & 7) << 3))];
#pragma unroll
      for (int ci = 0; ci < 4; ++ci) {
        const int bc = wid * 64 + ci * 16 + l15;
        const bf16x8 b = *(const bf16x8*)&Wbt[(size_t)bc * HID + kk + lk];
        acc[ci] = __builtin_amdgcn_mfma_f32_16x16x32_bf16(a, b, acc[ci], 0, 0, 0);
      }
    }

#pragma unroll
    for (int ci = 0; ci < 4; ++ci) {
      const int col = wid * 64 + ci * 16 + l15;
#pragma unroll
      for (int qq = 0; qq < 4; ++qq) {
        const int row = (lane >> 4) * 4 + qq;
        tb[row * 256 + (col ^ ((row & 7) << 3))] = f2bf(acc[ci][qq]);
      }
    }
  }
  __syncthreads();

#pragma unroll
  for (int i = 0; i < 2; ++i) {
    const int u = i * 256 + tid;
    const int kc = u >> 6, lr = (u >> 2) & 15, ks = u & 3;
    const int k = kc * 32 + ks * 8;
    const bf16x8 v = *(const bf16x8*)&tb[lr * 256 + (k ^ ((lr & 7) << 3))];
    *(bf16x8*)&Apk[(size_t)grp * 4096 + (size_t)u * 8] = v;
  }
}

// ---------------------------------------------------------------------------
// K2: logits = g @ hr^T + b_bil. 128x128 tile, 4 waves (2x2), 256 thr.
// HALF-K BULK STAGING: stage A+B for K=0..127 (64 KB LDS) in one async burst,
// ONE barrier, then 64 MFMAs with ZERO intermediate barriers (compiler's fine
// lgkmcnt orders ds_read->MFMA); barrier; restage K=128..255; barrier; compute.
// 3 barrier-drains per tile vs 8 in the per-kc dbuf loop. 64 KB LDS ->
// 2 blocks/CU for cross-block overlap of stage and compute phases.
// Row-band XCD swizzle (r8, proven). Cached logF stores (L3-resident for
// k_final). Epilogue: no-max exp partial-sum slabs (r12, proven).
// ---------------------------------------------------------------------------
__global__ __launch_bounds__(256) void k_gemm(
    const unsigned short* __restrict__ Apk,
    const unsigned short* __restrict__ Bpk,
    const float* __restrict__ b_bil,
    float* __restrict__ logF,
    float* __restrict__ rowPS,   // [96][NQ] partial sums over 64-col slabs
    float* __restrict__ colPS)   // [96][MR] partial sums over 64-row slabs
{
  const int tid = threadIdx.x;
  const int wid = tid >> 6, lane = tid & 63;
  const int wr = wid >> 1, wc = wid & 1;

  // XCD swizzle (2304 blocks, %8==0 -> bijective), bcol fastest per XCD
  const int orig = blockIdx.y * 48 + blockIdx.x;
  const int nid = (orig & 7) * 288 + (orig >> 3);
  const int brow = (nid / 48) * 128;              // slow: row band
  const int bcol = (nid % 48) * 128;              // fast: column sweep
  const int brow16 = brow >> 4, bcol16 = bcol >> 4;

  // [group][kci][512 shorts]: 8 groups x 4 kc-slices x 1 KB = 32 KB each
  __shared__ __align__(16) unsigned short As[8 * 4 * 512];
  __shared__ __align__(16) unsigned short Bs[8 * 4 * 512];

  const int l15 = lane & 15;
  const int ksg = lane >> 4;

  f32x4 acc[4][4];
#pragma unroll
  for (int i = 0; i < 4; ++i)
#pragma unroll
    for (int j = 0; j < 4; ++j) acc[i][j] = (f32x4)0.0f;

#pragma unroll
  for (int h = 0; h < 2; ++h) {
    // ---- bulk stage half h: each wave loads 2 A-groups + 2 B-groups x 4 kc ----
    if (h == 1) __syncthreads();  // all reads of half 0 done before overwrite
#pragma unroll
    for (int g2 = 0; g2 < 2; ++g2) {
      const int g = 2 * wid + g2;
      const size_t asrc = (size_t)(brow16 + g) * 4096 + h * 2048 + lane * 8;
      const size_t bsrc = (size_t)(bcol16 + g) * 4096 + h * 2048 + lane * 8;
#pragma unroll
      for (int kci = 0; kci < 4; ++kci) {
        gload16(Apk + asrc + kci * 512, &As[(g * 4 + kci) * 512]);
        gload16(Bpk + bsrc + kci * 512, &Bs[(g * 4 + kci) * 512]);
      }
    }
    __syncthreads();  // drains vmcnt: half h fully staged

    // ---- compute half h: 64 MFMAs, no barriers ----
#pragma unroll
    for (int kci = 0; kci < 4; ++kci) {
      const int fo = l15 * 32 + ksg * 8;
      bf16x8 a[4], b[4];
#pragma unroll
      for (int mi = 0; mi < 4; ++mi)
        a[mi] = *(const bf16x8*)&As[((wr * 4 + mi) * 4 + kci) * 512 + fo];
#pragma unroll
      for (int ni = 0; ni < 4; ++ni)
        b[ni] = *(const bf16x8*)&Bs[((wc * 4 + ni) * 4 + kci) * 512 + fo];
#pragma unroll
      for (int mi = 0; mi < 4; ++mi)
#pragma unroll
        for (int ni = 0; ni < 4; ++ni)
          acc[mi][ni] = __builtin_amdgcn_mfma_f32_16x16x32_bf16(
              a[mi], b[ni], acc[mi][ni], 0, 0, 0);
    }
  }

  const float bb = b_bil[0];
#pragma unroll
  for (int mi = 0; mi < 4; ++mi)
#pragma unroll
    for (int ni = 0; ni < 4; ++ni)
#pragma unroll
      for (int qq = 0; qq < 4; ++qq) acc[mi][ni][qq] += bb;

  const int r0 = brow + wr * 64 + ksg * 4;
  const int c0 = bcol + wc * 64 + l15;
#pragma unroll
  for (int mi = 0; mi < 4; ++mi)
#pragma unroll
    for (int qq = 0; qq < 4; ++qq) {
      const int rr = r0 + mi * 16 + qq;
#pragma unroll
      for (int ni = 0; ni < 4; ++ni)
        logF[(size_t)rr * MR + c0 + ni * 16] = acc[mi][ni][qq];  // cached store
    }

  // ---- no-max partial sums ----
  const int cb = (bcol >> 6) + wc;
  const int rb = (brow >> 6) + wr;
  float csum[4] = {0.0f, 0.0f, 0.0f, 0.0f};
#pragma unroll
  for (int mi = 0; mi < 4; ++mi) {
#pragma unroll
    for (int qq = 0; qq < 4; ++qq) {
      float rsum = 0.0f;
#pragma unroll
      for (int ni = 0; ni < 4; ++ni) {
        const float e = __expf(acc[mi][ni][qq] * INV_T);
        rsum += e;
        csum[ni] += e;
      }
      rsum += __shfl_xor(rsum, 1);
      rsum += __shfl_xor(rsum, 2);
      rsum += __shfl_xor(rsum, 4);
      rsum += __shfl_xor(rsum, 8);
      if (l15 == 0) rowPS[(size_t)cb * NQ + (r0 + mi * 16 + qq)] = rsum;
    }
  }
#pragma unroll
  for (int ni = 0; ni < 4; ++ni) {
    csum[ni] += __shfl_xor(csum[ni], 16);
    csum[ni] += __shfl_xor(csum[ni], 32);
  }
  if (lane < 16) {
#pragma unroll
    for (int ni = 0; ni < 4; ++ni)
      colPS[(size_t)rb * MR + (bcol + wc * 64 + ni * 16 + lane)] = csum[ni];
  }
}

// ---------------------------------------------------------------------------
// K3: combine 96 partial sums + slack; store 0.5/S.
// ---------------------------------------------------------------------------
__global__ __launch_bounds__(256) void k_comb(
    const float* __restrict__ rowPS, const float* __restrict__ colPS,
    const float* __restrict__ slack_q, const float* __restrict__ slack_ret,
    float* __restrict__ rowR, float* __restrict__ colR)
{
  const int idx = blockIdx.x * 256 + threadIdx.x;
  const bool is_row = idx < NQ;
  const int i = is_row ? idx : idx - NQ;
  const float* ps = is_row ? rowPS : colPS;

  float s = 0.0f;
  for (int c = 0; c < 96; ++c) s += ps[(size_t)c * NQ + i];
  s += __expf((is_row ? slack_q[0] : slack_ret[0]) * INV_T);

  if (is_row) rowR[i] = 0.5f / s;
  else        colR[i] = 0.5f / s;
}

// ---------------------------------------------------------------------------
// K4: pi = exp(l*10) * (0.5/S_r + 0.5/S_c). logF read is L3-hit (cached store
// in k_gemm); pi NT-stored (never re-read). Precomputed reciprocal tables.
// ---------------------------------------------------------------------------
__global__ __launch_bounds__(256) void k_final(
    const float* __restrict__ logF,
    const float* __restrict__ rowR, const float* __restrict__ colR,
    float* __restrict__ out_pi)
{
  const int row = blockIdx.x / 6;
  const int seg = blockIdx.x % 6;
  const int col = seg * 1024 + threadIdx.x * 4;
  const size_t base = (size_t)row * MR + col;

  const float rinv = rowR[row];
  const f32x4 cv = *(const f32x4*)(colR + col);
  const f32x4 l4 = *(const f32x4*)(logF + base);

  f32x4 o;
  o.x = __expf(l4.x * INV_T) * (rinv + cv.x);
  o.y = __expf(l4.y * INV_T) * (rinv + cv.y);
  o.z = __expf(l4.z * INV_T) * (rinv + cv.z);
  o.w = __expf(l4.w * INV_T) * (rinv + cv.w);
  __builtin_nontemporal_store(o, (f32x4*)(out_pi + base));
}

// ---------------------------------------------------------------------------
extern "C" void kernel_launch(void* const* d_in, const int* in_sizes, int n_in,
                              void* d_out, int out_size, void* d_ws, size_t ws_size,
                              hipStream_t stream) {
  const float* q  = (const float*)d_in[0];
  const float* r  = (const float*)d_in[1];
  const float* W1 = (const float*)d_in[2];
  const float* b1 = (const float*)d_in[3];
  const float* W2 = (const float*)d_in[4];
  const float* b2 = (const float*)d_in[5];
  const float* Wb = (const float*)d_in[6];
  const float* bb = (const float*)d_in[7];
  const float* sq = (const float*)d_in[8];
  const float* sr = (const float*)d_in[9];

  float* out_pi = (float*)d_out;                      // [NQ][MR] f32
  float* out_lg = out_pi + (size_t)NQ * MR;           // [NQ][MR] f32 logits

  char* w = (char*)d_ws;
  size_t off = 0;
  auto alloc = [&](size_t bytes) {
    void* p = w + off;
    off += (bytes + 255) & ~(size_t)255;
    return p;
  };
  unsigned short* Apk  = (unsigned short*)alloc((size_t)NQ * HID * 2);
  unsigned short* Bpk  = (unsigned short*)alloc((size_t)MR * HID * 2);
  unsigned short* W2bf = (unsigned short*)alloc((size_t)HID * HID * 2);
  unsigned short* Wbt  = (unsigned short*)alloc((size_t)HID * HID * 2);
  float* rowR = (float*)alloc((size_t)NQ * 4);
  float* colR = (float*)alloc((size_t)MR * 4);

  // Partial-sum slabs live in out_pi (dead until k_final rewrites it);
  // k_comb consumes them before k_final runs (stream order).
  float* rowPS = out_pi + (size_t)0 * 96 * NQ;
  float* colPS = out_pi + (size_t)1 * 96 * NQ;

  k_prep<<<dim3(HID * HID / 256), 256, 0, stream>>>(W2, Wb, W2bf, Wbt);
  k_compress<<<dim3((NQ + MR) / 16), 256, 0, stream>>>(q, r, W1, b1, W2bf, b2,
                                                       Wbt, Apk, Bpk);
  k_gemm<<<dim3(48, 48), 256, 0, stream>>>(Apk, Bpk, bb, out_lg, rowPS, colPS);
  k_comb<<<dim3((NQ + MR) / 256), 256, 0, stream>>>(
      rowPS, colPS, sq, sr, rowR, colR);
  k_final<<<dim3(NQ * 6), 256, 0, stream>>>(out_lg, rowR, colR, out_pi);
}

// Round 15
// 134.506 us; speedup vs baseline: 1.0292x; 1.0292x over previous
//
#include <hip/hip_runtime.h>
#include <hip/hip_bf16.h>
#include <math.h>

#define NQ 6144
#define MR 6144
#define DIN 16
#define HID 256
#define INV_T 10.0f

typedef __attribute__((ext_vector_type(4))) float f32x4;
typedef __attribute__((ext_vector_type(8))) short bf16x8;

// Packed fragment-major operand layout (shorts):
//   pk[group][kc][l15][ksub*8 + j], group = row/16, kc = k/32, ksub = (k%32)/8
//   short offset = group*4096 + kc*512 + l15*32 + ksub*8
// A (group,kc) K-slice is a contiguous 1 KB -> ideal for global_load_lds
// (linear dest) and its ds_read frag pattern is bank-uniform (no swizzle).

static __device__ __forceinline__ unsigned short f2bf(float f) {
  __hip_bfloat16 h = __float2bfloat16(f);
  return __builtin_bit_cast(unsigned short, h);
}

// async global->LDS, 16 B per lane. LDS base must be wave-uniform.
static __device__ __forceinline__ void gload16(const void* g, void* l) {
  __builtin_amdgcn_global_load_lds(
      (const __attribute__((address_space(1))) unsigned int*)g,
      (__attribute__((address_space(3))) unsigned int*)l, 16, 0, 0);
}

// ---------------------------------------------------------------------------
// K0: prep — W2 -> bf16 (row-major), Wb -> bf16 transposed.
// ---------------------------------------------------------------------------
__global__ __launch_bounds__(256) void k_prep(
    const float* __restrict__ W2, const float* __restrict__ Wb,
    unsigned short* __restrict__ W2bf, unsigned short* __restrict__ Wbt)
{
  const int idx = blockIdx.x * 256 + threadIdx.x;  // = j*256 + c
  W2bf[idx] = f2bf(W2[idx]);
  const int j = idx >> 8, c = idx & 255;
  Wbt[(size_t)c * 256 + j] = f2bf(Wb[idx]);
}

// ---------------------------------------------------------------------------
// K1: compress (MFMA). 16 rows/block = one packed group, 256 thr (4 waves).
// ---------------------------------------------------------------------------
__global__ __launch_bounds__(256) void k_compress(
    const float* __restrict__ q, const float* __restrict__ ret,
    const float* __restrict__ W1, const float* __restrict__ b1,
    const unsigned short* __restrict__ W2bf, const float* __restrict__ b2,
    const unsigned short* __restrict__ Wbt,
    unsigned short* __restrict__ Apk, unsigned short* __restrict__ Bpk)
{
  const int tid = threadIdx.x;
  const bool is_q = blockIdx.x < (NQ / 16);
  const int grp = is_q ? blockIdx.x : blockIdx.x - NQ / 16;
  const int row0 = grp * 16;
  const float* x = is_q ? q : ret;

  __shared__ float xs[16][DIN];
  __shared__ __align__(16) unsigned short tb[16 * 256];
  __shared__ __align__(16) unsigned short hb[16 * 256];

  ((float*)xs)[tid] = x[(size_t)row0 * DIN + tid];
  __syncthreads();

  // ---- phase 1: gelu(x@W1^T + b1) -> tb (bf16, swizzled) ----
  {
    float w[DIN];
#pragma unroll
    for (int d = 0; d < DIN; ++d) w[d] = W1[tid * DIN + d];
    const float bb = b1[tid];
#pragma unroll
    for (int rr = 0; rr < 16; ++rr) {
      float a = bb;
#pragma unroll
      for (int d = 0; d < DIN; ++d) a += xs[rr][d] * w[d];
      a = 0.5f * a * (1.0f + erff(a * 0.70710678118654752f));
      tb[rr * 256 + (tid ^ ((rr & 7) << 3))] = f2bf(a);
    }
  }
  __syncthreads();

  const int wid = tid >> 6, lane = tid & 63;
  const int l15 = lane & 15;
  const int lk = (lane >> 4) * 8;

  // ---- phase 2: h = t @ W2^T + b2 -> hb ----
  {
    f32x4 acc[4];
#pragma unroll
    for (int ci = 0; ci < 4; ++ci) acc[ci] = (f32x4)0.0f;

    for (int kk = 0; kk < HID; kk += 32) {
      const bf16x8 a = *(const bf16x8*)&tb[l15 * 256 + ((kk + lk) ^ ((l15 & 7) << 3))];
#pragma unroll
      for (int ci = 0; ci < 4; ++ci) {
        const int bc = wid * 64 + ci * 16 + l15;
        const bf16x8 b = *(const bf16x8*)&W2bf[(size_t)bc * HID + kk + lk];
        acc[ci] = __builtin_amdgcn_mfma_f32_16x16x32_bf16(a, b, acc[ci], 0, 0, 0);
      }
    }

#pragma unroll
    for (int ci = 0; ci < 4; ++ci) {
      const int col = wid * 64 + ci * 16 + l15;
      const float bb2 = b2[col];
#pragma unroll
      for (int qq = 0; qq < 4; ++qq) {
        const int row = (lane >> 4) * 4 + qq;
        hb[row * 256 + (col ^ ((row & 7) << 3))] = f2bf(acc[ci][qq] + bb2);
      }
    }
  }
  __syncthreads();

  if (!is_q) {
#pragma unroll
    for (int i = 0; i < 2; ++i) {
      const int u = i * 256 + tid;
      const int kc = u >> 6, lr = (u >> 2) & 15, ks = u & 3;
      const int k = kc * 32 + ks * 8;
      const bf16x8 v = *(const bf16x8*)&hb[lr * 256 + (k ^ ((lr & 7) << 3))];
      *(bf16x8*)&Bpk[(size_t)grp * 4096 + (size_t)u * 8] = v;
    }
    return;
  }

  // ---- phase 3 (q only): g = h @ Wb ----
  {
    f32x4 acc[4];
#pragma unroll
    for (int ci = 0; ci < 4; ++ci) acc[ci] = (f32x4)0.0f;

    for (int kk = 0; kk < HID; kk += 32) {
      const bf16x8 a = *(const bf16x8*)&hb[l15 * 256 + ((kk + lk) ^ ((l15 & 7) << 3))];
#pragma unroll
      for (int ci = 0; ci < 4; ++ci) {
        const int bc = wid * 64 + ci * 16 + l15;
        const bf16x8 b = *(const bf16x8*)&Wbt[(size_t)bc * HID + kk + lk];
        acc[ci] = __builtin_amdgcn_mfma_f32_16x16x32_bf16(a, b, acc[ci], 0, 0, 0);
      }
    }

#pragma unroll
    for (int ci = 0; ci < 4; ++ci) {
      const int col = wid * 64 + ci * 16 + l15;
#pragma unroll
      for (int qq = 0; qq < 4; ++qq) {
        const int row = (lane >> 4) * 4 + qq;
        tb[row * 256 + (col ^ ((row & 7) << 3))] = f2bf(acc[ci][qq]);
      }
    }
  }
  __syncthreads();

#pragma unroll
  for (int i = 0; i < 2; ++i) {
    const int u = i * 256 + tid;
    const int kc = u >> 6, lr = (u >> 2) & 15, ks = u & 3;
    const int k = kc * 32 + ks * 8;
    const bf16x8 v = *(const bf16x8*)&tb[lr * 256 + (k ^ ((lr & 7) << 3))];
    *(bf16x8*)&Apk[(size_t)grp * 4096 + (size_t)u * 8] = v;
  }
}

// ---------------------------------------------------------------------------
// K2: logits = g @ hr^T + b_bil. 256x128 tile, 8 waves (4x2), 512 thr,
// dbuf LDS via global_load_lds. Row-band XCD swizzle (bcol fastest).
// Cached logF stores (L3-resident for k_final; NT here cost +16 µs — r12).
// Epilogue: no-max exp partial-sum slabs.
// ---------------------------------------------------------------------------
__global__ __launch_bounds__(512, 4) void k_gemm(
    const unsigned short* __restrict__ Apk,
    const unsigned short* __restrict__ Bpk,
    const float* __restrict__ b_bil,
    float* __restrict__ logF,
    float* __restrict__ rowPS,   // [96][NQ] partial sums over 64-col slabs
    float* __restrict__ colPS)   // [96][MR] partial sums over 64-row slabs
{
  const int tid = threadIdx.x;
  const int wid = tid >> 6, lane = tid & 63;
  const int wr = wid >> 1, wc = wid & 1;       // 4 row-waves x 2 col-waves

  // XCD swizzle (nwg = 48*24 = 1152, %8==0 -> bijective), bcol fastest
  const int orig = blockIdx.y * 48 + blockIdx.x;
  const int nid = (orig & 7) * 144 + (orig >> 3);
  const int brow = (nid / 48) * 256;           // slow: 256-row band
  const int bcol = (nid % 48) * 128;           // fast: column sweep
  const int brow16 = brow >> 4, bcol16 = bcol >> 4;

  __shared__ __align__(16) unsigned short As[2][8192];  // 16 groups x 1KB
  __shared__ __align__(16) unsigned short Bs[2][4096];  //  8 groups x 1KB

  const int l15 = lane & 15;
  const int ksg = lane >> 4;

  f32x4 acc[4][4];
#pragma unroll
  for (int i = 0; i < 4; ++i)
#pragma unroll
    for (int j = 0; j < 4; ++j) acc[i][j] = (f32x4)0.0f;

  // stage kc=0: wave w loads A groups 2w,2w+1 and B group w (1 KB each)
  gload16(Apk + (size_t)(brow16 + 2 * wid) * 4096 + lane * 8,
          &As[0][(2 * wid) * 512]);
  gload16(Apk + (size_t)(brow16 + 2 * wid + 1) * 4096 + lane * 8,
          &As[0][(2 * wid + 1) * 512]);
  gload16(Bpk + (size_t)(bcol16 + wid) * 4096 + lane * 8, &Bs[0][wid * 512]);

  int cur = 0;
  for (int kc = 0; kc < 8; ++kc) {
    __syncthreads();  // drains vmcnt (buf[cur] staged) + lgkm (prev reads)
    if (kc < 7) {
      const int kn = (kc + 1) * 512;
      gload16(Apk + (size_t)(brow16 + 2 * wid) * 4096 + kn + lane * 8,
              &As[cur ^ 1][(2 * wid) * 512]);
      gload16(Apk + (size_t)(brow16 + 2 * wid + 1) * 4096 + kn + lane * 8,
              &As[cur ^ 1][(2 * wid + 1) * 512]);
      gload16(Bpk + (size_t)(bcol16 + wid) * 4096 + kn + lane * 8,
              &Bs[cur ^ 1][wid * 512]);
    }
    const int fo = l15 * 32 + ksg * 8;
    bf16x8 a[4], b[4];
#pragma unroll
    for (int mi = 0; mi < 4; ++mi)
      a[mi] = *(const bf16x8*)&As[cur][(wr * 4 + mi) * 512 + fo];
#pragma unroll
    for (int ni = 0; ni < 4; ++ni)
      b[ni] = *(const bf16x8*)&Bs[cur][(wc * 4 + ni) * 512 + fo];
#pragma unroll
    for (int mi = 0; mi < 4; ++mi)
#pragma unroll
      for (int ni = 0; ni < 4; ++ni)
        acc[mi][ni] = __builtin_amdgcn_mfma_f32_16x16x32_bf16(
            a[mi], b[ni], acc[mi][ni], 0, 0, 0);
    cur ^= 1;
  }

  const float bb = b_bil[0];
#pragma unroll
  for (int mi = 0; mi < 4; ++mi)
#pragma unroll
    for (int ni = 0; ni < 4; ++ni)
#pragma unroll
      for (int qq = 0; qq < 4; ++qq) acc[mi][ni][qq] += bb;

  const int r0 = brow + wr * 64 + ksg * 4;
  const int c0 = bcol + wc * 64 + l15;
#pragma unroll
  for (int mi = 0; mi < 4; ++mi)
#pragma unroll
    for (int qq = 0; qq < 4; ++qq) {
      const int rr = r0 + mi * 16 + qq;
#pragma unroll
      for (int ni = 0; ni < 4; ++ni)
        logF[(size_t)rr * MR + c0 + ni * 16] = acc[mi][ni][qq];  // cached store
    }

  // ---- no-max partial sums ----
  const int cb = (bcol >> 6) + wc;
  const int rb = (brow >> 6) + wr;
  float csum[4] = {0.0f, 0.0f, 0.0f, 0.0f};
#pragma unroll
  for (int mi = 0; mi < 4; ++mi) {
#pragma unroll
    for (int qq = 0; qq < 4; ++qq) {
      float rsum = 0.0f;
#pragma unroll
      for (int ni = 0; ni < 4; ++ni) {
        const float e = __expf(acc[mi][ni][qq] * INV_T);
        rsum += e;
        csum[ni] += e;
      }
      rsum += __shfl_xor(rsum, 1);
      rsum += __shfl_xor(rsum, 2);
      rsum += __shfl_xor(rsum, 4);
      rsum += __shfl_xor(rsum, 8);
      if (l15 == 0) rowPS[(size_t)cb * NQ + (r0 + mi * 16 + qq)] = rsum;
    }
  }
#pragma unroll
  for (int ni = 0; ni < 4; ++ni) {
    csum[ni] += __shfl_xor(csum[ni], 16);
    csum[ni] += __shfl_xor(csum[ni], 32);
  }
  if (lane < 16) {
#pragma unroll
    for (int ni = 0; ni < 4; ++ni)
      colPS[(size_t)rb * MR + (bcol + wc * 64 + ni * 16 + lane)] = csum[ni];
  }
}

// ---------------------------------------------------------------------------
// K3: combine 96 partial sums + slack; store 0.5/S.
// ---------------------------------------------------------------------------
__global__ __launch_bounds__(256) void k_comb(
    const float* __restrict__ rowPS, const float* __restrict__ colPS,
    const float* __restrict__ slack_q, const float* __restrict__ slack_ret,
    float* __restrict__ rowR, float* __restrict__ colR)
{
  const int idx = blockIdx.x * 256 + threadIdx.x;
  const bool is_row = idx < NQ;
  const int i = is_row ? idx : idx - NQ;
  const float* ps = is_row ? rowPS : colPS;

  float s = 0.0f;
  for (int c = 0; c < 96; ++c) s += ps[(size_t)c * NQ + i];
  s += __expf((is_row ? slack_q[0] : slack_ret[0]) * INV_T);

  if (is_row) rowR[i] = 0.5f / s;
  else        colR[i] = 0.5f / s;
}

// ---------------------------------------------------------------------------
// K4: pi = exp(l*10) * (0.5/S_r + 0.5/S_c). logF read is L3-hit (cached store
// in k_gemm); pi NT-stored (never re-read). Precomputed reciprocal tables.
// 8 floats/thread (widened vs r12's 4 — fewer blocks, wider streams).
// ---------------------------------------------------------------------------
__global__ __launch_bounds__(256) void k_final(
    const float* __restrict__ logF,
    const float* __restrict__ rowR, const float* __restrict__ colR,
    float* __restrict__ out_pi)
{
  const int row = blockIdx.x / 3;
  const int seg = blockIdx.x % 3;
  const int col = seg * 2048 + threadIdx.x * 8;
  const size_t base = (size_t)row * MR + col;

  const float rinv = rowR[row];
  const f32x4 cv0 = *(const f32x4*)(colR + col);
  const f32x4 cv1 = *(const f32x4*)(colR + col + 4);
  const f32x4 l0 = *(const f32x4*)(logF + base);
  const f32x4 l1 = *(const f32x4*)(logF + base + 4);

  f32x4 o0, o1;
  o0.x = __expf(l0.x * INV_T) * (rinv + cv0.x);
  o0.y = __expf(l0.y * INV_T) * (rinv + cv0.y);
  o0.z = __expf(l0.z * INV_T) * (rinv + cv0.z);
  o0.w = __expf(l0.w * INV_T) * (rinv + cv0.w);
  o1.x = __expf(l1.x * INV_T) * (rinv + cv1.x);
  o1.y = __expf(l1.y * INV_T) * (rinv + cv1.y);
  o1.z = __expf(l1.z * INV_T) * (rinv + cv1.z);
  o1.w = __expf(l1.w * INV_T) * (rinv + cv1.w);
  __builtin_nontemporal_store(o0, (f32x4*)(out_pi + base));
  __builtin_nontemporal_store(o1, (f32x4*)(out_pi + base + 4));
}

// ---------------------------------------------------------------------------
extern "C" void kernel_launch(void* const* d_in, const int* in_sizes, int n_in,
                              void* d_out, int out_size, void* d_ws, size_t ws_size,
                              hipStream_t stream) {
  const float* q  = (const float*)d_in[0];
  const float* r  = (const float*)d_in[1];
  const float* W1 = (const float*)d_in[2];
  const float* b1 = (const float*)d_in[3];
  const float* W2 = (const float*)d_in[4];
  const float* b2 = (const float*)d_in[5];
  const float* Wb = (const float*)d_in[6];
  const float* bb = (const float*)d_in[7];
  const float* sq = (const float*)d_in[8];
  const float* sr = (const float*)d_in[9];

  float* out_pi = (float*)d_out;                      // [NQ][MR] f32
  float* out_lg = out_pi + (size_t)NQ * MR;           // [NQ][MR] f32 logits

  char* w = (char*)d_ws;
  size_t off = 0;
  auto alloc = [&](size_t bytes) {
    void* p = w + off;
    off += (bytes + 255) & ~(size_t)255;
    return p;
  };
  unsigned short* Apk  = (unsigned short*)alloc((size_t)NQ * HID * 2);
  unsigned short* Bpk  = (unsigned short*)alloc((size_t)MR * HID * 2);
  unsigned short* W2bf = (unsigned short*)alloc((size_t)HID * HID * 2);
  unsigned short* Wbt  = (unsigned short*)alloc((size_t)HID * HID * 2);
  float* rowR = (float*)alloc((size_t)NQ * 4);
  float* colR = (float*)alloc((size_t)MR * 4);

  // Partial-sum slabs live in out_pi (dead until k_final rewrites it);
  // k_comb consumes them before k_final runs (stream order).
  float* rowPS = out_pi + (size_t)0 * 96 * NQ;
  float* colPS = out_pi + (size_t)1 * 96 * NQ;

  k_prep<<<dim3(HID * HID / 256), 256, 0, stream>>>(W2, Wb, W2bf, Wbt);
  k_compress<<<dim3((NQ + MR) / 16), 256, 0, stream>>>(q, r, W1, b1, W2bf, b2,
                                                       Wbt, Apk, Bpk);
  k_gemm<<<dim3(48, 24), 512, 0, stream>>>(Apk, Bpk, bb, out_lg, rowPS, colPS);
  k_comb<<<dim3((NQ + MR) / 256), 256, 0, stream>>>(
      rowPS, colPS, sq, sr, rowR, colR);
  k_final<<<dim3(NQ * 3), 256, 0, stream>>>(out_lg, rowR, colR, out_pi);
}

// Round 16
// 127.933 us; speedup vs baseline: 1.0821x; 1.0514x over previous
//
#include <hip/hip_runtime.h>
#include <hip/hip_bf16.h>
#include <math.h>

#define NQ 6144
#define MR 6144
#define DIN 16
#define HID 256
#define INV_T 10.0f

typedef __attribute__((ext_vector_type(4))) float f32x4;
typedef __attribute__((ext_vector_type(8))) short bf16x8;

// Packed fragment-major operand layout (shorts):
//   pk[group][kc][l15][ksub*8 + j], group = row/16, kc = k/32, ksub = (k%32)/8
//   short offset = group*4096 + kc*512 + l15*32 + ksub*8
// A (group,kc) K-slice is a contiguous 1 KB -> ideal for global_load_lds
// (linear dest) and its ds_read frag pattern is bank-uniform (no swizzle).

static __device__ __forceinline__ unsigned short f2bf(float f) {
  __hip_bfloat16 h = __float2bfloat16(f);
  return __builtin_bit_cast(unsigned short, h);
}

// async global->LDS, 16 B per lane. LDS base must be wave-uniform.
static __device__ __forceinline__ void gload16(const void* g, void* l) {
  __builtin_amdgcn_global_load_lds(
      (const __attribute__((address_space(1))) unsigned int*)g,
      (__attribute__((address_space(3))) unsigned int*)l, 16, 0, 0);
}

// ---------------------------------------------------------------------------
// K0: prep — W2 -> bf16 (row-major), Wb -> bf16 transposed.
// ---------------------------------------------------------------------------
__global__ __launch_bounds__(256) void k_prep(
    const float* __restrict__ W2, const float* __restrict__ Wb,
    unsigned short* __restrict__ W2bf, unsigned short* __restrict__ Wbt)
{
  const int idx = blockIdx.x * 256 + threadIdx.x;  // = j*256 + c
  W2bf[idx] = f2bf(W2[idx]);
  const int j = idx >> 8, c = idx & 255;
  Wbt[(size_t)c * 256 + j] = f2bf(Wb[idx]);
}

// ---------------------------------------------------------------------------
// K1: compress (MFMA). 16 rows/block = one packed group, 256 thr (4 waves).
// ---------------------------------------------------------------------------
__global__ __launch_bounds__(256) void k_compress(
    const float* __restrict__ q, const float* __restrict__ ret,
    const float* __restrict__ W1, const float* __restrict__ b1,
    const unsigned short* __restrict__ W2bf, const float* __restrict__ b2,
    const unsigned short* __restrict__ Wbt,
    unsigned short* __restrict__ Apk, unsigned short* __restrict__ Bpk)
{
  const int tid = threadIdx.x;
  const bool is_q = blockIdx.x < (NQ / 16);
  const int grp = is_q ? blockIdx.x : blockIdx.x - NQ / 16;
  const int row0 = grp * 16;
  const float* x = is_q ? q : ret;

  __shared__ float xs[16][DIN];
  __shared__ __align__(16) unsigned short tb[16 * 256];
  __shared__ __align__(16) unsigned short hb[16 * 256];

  ((float*)xs)[tid] = x[(size_t)row0 * DIN + tid];
  __syncthreads();

  // ---- phase 1: gelu(x@W1^T + b1) -> tb (bf16, swizzled) ----
  {
    float w[DIN];
#pragma unroll
    for (int d = 0; d < DIN; ++d) w[d] = W1[tid * DIN + d];
    const float bb = b1[tid];
#pragma unroll
    for (int rr = 0; rr < 16; ++rr) {
      float a = bb;
#pragma unroll
      for (int d = 0; d < DIN; ++d) a += xs[rr][d] * w[d];
      a = 0.5f * a * (1.0f + erff(a * 0.70710678118654752f));
      tb[rr * 256 + (tid ^ ((rr & 7) << 3))] = f2bf(a);
    }
  }
  __syncthreads();

  const int wid = tid >> 6, lane = tid & 63;
  const int l15 = lane & 15;
  const int lk = (lane >> 4) * 8;

  // ---- phase 2: h = t @ W2^T + b2 -> hb ----
  {
    f32x4 acc[4];
#pragma unroll
    for (int ci = 0; ci < 4; ++ci) acc[ci] = (f32x4)0.0f;

    for (int kk = 0; kk < HID; kk += 32) {
      const bf16x8 a = *(const bf16x8*)&tb[l15 * 256 + ((kk + lk) ^ ((l15 & 7) << 3))];
#pragma unroll
      for (int ci = 0; ci < 4; ++ci) {
        const int bc = wid * 64 + ci * 16 + l15;
        const bf16x8 b = *(const bf16x8*)&W2bf[(size_t)bc * HID + kk + lk];
        acc[ci] = __builtin_amdgcn_mfma_f32_16x16x32_bf16(a, b, acc[ci], 0, 0, 0);
      }
    }

#pragma unroll
    for (int ci = 0; ci < 4; ++ci) {
      const int col = wid * 64 + ci * 16 + l15;
      const float bb2 = b2[col];
#pragma unroll
      for (int qq = 0; qq < 4; ++qq) {
        const int row = (lane >> 4) * 4 + qq;
        hb[row * 256 + (col ^ ((row & 7) << 3))] = f2bf(acc[ci][qq] + bb2);
      }
    }
  }
  __syncthreads();

  if (!is_q) {
#pragma unroll
    for (int i = 0; i < 2; ++i) {
      const int u = i * 256 + tid;
      const int kc = u >> 6, lr = (u >> 2) & 15, ks = u & 3;
      const int k = kc * 32 + ks * 8;
      const bf16x8 v = *(const bf16x8*)&hb[lr * 256 + (k ^ ((lr & 7) << 3))];
      *(bf16x8*)&Bpk[(size_t)grp * 4096 + (size_t)u * 8] = v;
    }
    return;
  }

  // ---- phase 3 (q only): g = h @ Wb ----
  {
    f32x4 acc[4];
#pragma unroll
    for (int ci = 0; ci < 4; ++ci) acc[ci] = (f32x4)0.0f;

    for (int kk = 0; kk < HID; kk += 32) {
      const bf16x8 a = *(const bf16x8*)&hb[l15 * 256 + ((kk + lk) ^ ((l15 & 7) << 3))];
#pragma unroll
      for (int ci = 0; ci < 4; ++ci) {
        const int bc = wid * 64 + ci * 16 + l15;
        const bf16x8 b = *(const bf16x8*)&Wbt[(size_t)bc * HID + kk + lk];
        acc[ci] = __builtin_amdgcn_mfma_f32_16x16x32_bf16(a, b, acc[ci], 0, 0, 0);
      }
    }

#pragma unroll
    for (int ci = 0; ci < 4; ++ci) {
      const int col = wid * 64 + ci * 16 + l15;
#pragma unroll
      for (int qq = 0; qq < 4; ++qq) {
        const int row = (lane >> 4) * 4 + qq;
        tb[row * 256 + (col ^ ((row & 7) << 3))] = f2bf(acc[ci][qq]);
      }
    }
  }
  __syncthreads();

#pragma unroll
  for (int i = 0; i < 2; ++i) {
    const int u = i * 256 + tid;
    const int kc = u >> 6, lr = (u >> 2) & 15, ks = u & 3;
    const int k = kc * 32 + ks * 8;
    const bf16x8 v = *(const bf16x8*)&tb[lr * 256 + (k ^ ((lr & 7) << 3))];
    *(bf16x8*)&Apk[(size_t)grp * 4096 + (size_t)u * 8] = v;
  }
}

// ---------------------------------------------------------------------------
// K2: logits = g @ hr^T + b_bil. 256x128 tile, 8 waves (4x2), 512 thr,
// dbuf LDS via global_load_lds. Row-band XCD swizzle (bcol fastest).
// logF stored with PLAIN cached stores: logF (151 MB) fits the 256 MB L3 and
// k_final re-reads it immediately — NT stores here cost +16 µs (r11 vs r12).
// pi remains NT in k_final (never re-read).
// ---------------------------------------------------------------------------
__global__ __launch_bounds__(512, 4) void k_gemm(
    const unsigned short* __restrict__ Apk,
    const unsigned short* __restrict__ Bpk,
    const float* __restrict__ b_bil,
    float* __restrict__ logF,
    float* __restrict__ rowPS,   // [96][NQ] partial sums over 64-col slabs
    float* __restrict__ colPS)   // [96][MR] partial sums over 64-row slabs
{
  const int tid = threadIdx.x;
  const int wid = tid >> 6, lane = tid & 63;
  const int wr = wid >> 1, wc = wid & 1;       // 4 row-waves x 2 col-waves

  // XCD swizzle (nwg = 48*24 = 1152, %8==0 -> bijective), bcol fastest
  const int orig = blockIdx.y * 48 + blockIdx.x;
  const int nid = (orig & 7) * 144 + (orig >> 3);
  const int brow = (nid / 48) * 256;           // slow: 256-row band
  const int bcol = (nid % 48) * 128;           // fast: column sweep
  const int brow16 = brow >> 4, bcol16 = bcol >> 4;

  __shared__ __align__(16) unsigned short As[2][8192];  // 16 groups x 1KB
  __shared__ __align__(16) unsigned short Bs[2][4096];  //  8 groups x 1KB

  const int l15 = lane & 15;
  const int ksg = lane >> 4;

  f32x4 acc[4][4];
#pragma unroll
  for (int i = 0; i < 4; ++i)
#pragma unroll
    for (int j = 0; j < 4; ++j) acc[i][j] = (f32x4)0.0f;

  // stage kc=0: wave w loads A groups 2w,2w+1 and B group w (1 KB each)
  gload16(Apk + (size_t)(brow16 + 2 * wid) * 4096 + lane * 8,
          &As[0][(2 * wid) * 512]);
  gload16(Apk + (size_t)(brow16 + 2 * wid + 1) * 4096 + lane * 8,
          &As[0][(2 * wid + 1) * 512]);
  gload16(Bpk + (size_t)(bcol16 + wid) * 4096 + lane * 8, &Bs[0][wid * 512]);

  int cur = 0;
  for (int kc = 0; kc < 8; ++kc) {
    __syncthreads();  // drains vmcnt (buf[cur] staged) + lgkm (prev reads)
    if (kc < 7) {
      const int kn = (kc + 1) * 512;
      gload16(Apk + (size_t)(brow16 + 2 * wid) * 4096 + kn + lane * 8,
              &As[cur ^ 1][(2 * wid) * 512]);
      gload16(Apk + (size_t)(brow16 + 2 * wid + 1) * 4096 + kn + lane * 8,
              &As[cur ^ 1][(2 * wid + 1) * 512]);
      gload16(Bpk + (size_t)(bcol16 + wid) * 4096 + kn + lane * 8,
              &Bs[cur ^ 1][wid * 512]);
    }
    const int fo = l15 * 32 + ksg * 8;
    bf16x8 a[4], b[4];
#pragma unroll
    for (int mi = 0; mi < 4; ++mi)
      a[mi] = *(const bf16x8*)&As[cur][(wr * 4 + mi) * 512 + fo];
#pragma unroll
    for (int ni = 0; ni < 4; ++ni)
      b[ni] = *(const bf16x8*)&Bs[cur][(wc * 4 + ni) * 512 + fo];
#pragma unroll
    for (int mi = 0; mi < 4; ++mi)
#pragma unroll
      for (int ni = 0; ni < 4; ++ni)
        acc[mi][ni] = __builtin_amdgcn_mfma_f32_16x16x32_bf16(
            a[mi], b[ni], acc[mi][ni], 0, 0, 0);
    cur ^= 1;
  }

  const float bb = b_bil[0];
#pragma unroll
  for (int mi = 0; mi < 4; ++mi)
#pragma unroll
    for (int ni = 0; ni < 4; ++ni)
#pragma unroll
      for (int qq = 0; qq < 4; ++qq) acc[mi][ni][qq] += bb;

  const int r0 = brow + wr * 64 + ksg * 4;
  const int c0 = bcol + wc * 64 + l15;
#pragma unroll
  for (int mi = 0; mi < 4; ++mi)
#pragma unroll
    for (int qq = 0; qq < 4; ++qq) {
      const int rr = r0 + mi * 16 + qq;
#pragma unroll
      for (int ni = 0; ni < 4; ++ni)
        logF[(size_t)rr * MR + c0 + ni * 16] = acc[mi][ni][qq];  // cached store
    }

  // ---- no-max partial sums ----
  const int cb = (bcol >> 6) + wc;
  const int rb = (brow >> 6) + wr;
  float csum[4] = {0.0f, 0.0f, 0.0f, 0.0f};
#pragma unroll
  for (int mi = 0; mi < 4; ++mi) {
#pragma unroll
    for (int qq = 0; qq < 4; ++qq) {
      float rsum = 0.0f;
#pragma unroll
      for (int ni = 0; ni < 4; ++ni) {
        const float e = __expf(acc[mi][ni][qq] * INV_T);
        rsum += e;
        csum[ni] += e;
      }
      rsum += __shfl_xor(rsum, 1);
      rsum += __shfl_xor(rsum, 2);
      rsum += __shfl_xor(rsum, 4);
      rsum += __shfl_xor(rsum, 8);
      if (l15 == 0) rowPS[(size_t)cb * NQ + (r0 + mi * 16 + qq)] = rsum;
    }
  }
#pragma unroll
  for (int ni = 0; ni < 4; ++ni) {
    csum[ni] += __shfl_xor(csum[ni], 16);
    csum[ni] += __shfl_xor(csum[ni], 32);
  }
  if (lane < 16) {
#pragma unroll
    for (int ni = 0; ni < 4; ++ni)
      colPS[(size_t)rb * MR + (bcol + wc * 64 + ni * 16 + lane)] = csum[ni];
  }
}

// ---------------------------------------------------------------------------
// K3: combine 96 partial sums + slack; store 0.5/S.
// ---------------------------------------------------------------------------
__global__ __launch_bounds__(256) void k_comb(
    const float* __restrict__ rowPS, const float* __restrict__ colPS,
    const float* __restrict__ slack_q, const float* __restrict__ slack_ret,
    float* __restrict__ rowR, float* __restrict__ colR)
{
  const int idx = blockIdx.x * 256 + threadIdx.x;
  const bool is_row = idx < NQ;
  const int i = is_row ? idx : idx - NQ;
  const float* ps = is_row ? rowPS : colPS;

  float s = 0.0f;
  for (int c = 0; c < 96; ++c) s += ps[(size_t)c * NQ + i];
  s += __expf((is_row ? slack_q[0] : slack_ret[0]) * INV_T);

  if (is_row) rowR[i] = 0.5f / s;
  else        colR[i] = 0.5f / s;
}

// ---------------------------------------------------------------------------
// K4: pi = exp(l*10) * (0.5/S_r + 0.5/S_c). logF read is L3-hit (cached store
// in k_gemm); pi NT-stored (never re-read). 4 floats/thread, 1024-col
// segments (measured optimum — widening to 8 cost ~6 µs, r15).
// ---------------------------------------------------------------------------
__global__ __launch_bounds__(256) void k_final(
    const float* __restrict__ logF,
    const float* __restrict__ rowR, const float* __restrict__ colR,
    float* __restrict__ out_pi)
{
  const int row = blockIdx.x / 6;
  const int seg = blockIdx.x % 6;
  const int col = seg * 1024 + threadIdx.x * 4;
  const size_t base = (size_t)row * MR + col;

  const float rinv = rowR[row];
  const f32x4 cv = *(const f32x4*)(colR + col);
  const f32x4 l4 = *(const f32x4*)(logF + base);

  f32x4 o;
  o.x = __expf(l4.x * INV_T) * (rinv + cv.x);
  o.y = __expf(l4.y * INV_T) * (rinv + cv.y);
  o.z = __expf(l4.z * INV_T) * (rinv + cv.z);
  o.w = __expf(l4.w * INV_T) * (rinv + cv.w);
  __builtin_nontemporal_store(o, (f32x4*)(out_pi + base));
}

// ---------------------------------------------------------------------------
extern "C" void kernel_launch(void* const* d_in, const int* in_sizes, int n_in,
                              void* d_out, int out_size, void* d_ws, size_t ws_size,
                              hipStream_t stream) {
  const float* q  = (const float*)d_in[0];
  const float* r  = (const float*)d_in[1];
  const float* W1 = (const float*)d_in[2];
  const float* b1 = (const float*)d_in[3];
  const float* W2 = (const float*)d_in[4];
  const float* b2 = (const float*)d_in[5];
  const float* Wb = (const float*)d_in[6];
  const float* bb = (const float*)d_in[7];
  const float* sq = (const float*)d_in[8];
  const float* sr = (const float*)d_in[9];

  float* out_pi = (float*)d_out;                      // [NQ][MR] f32
  float* out_lg = out_pi + (size_t)NQ * MR;           // [NQ][MR] f32 logits

  char* w = (char*)d_ws;
  size_t off = 0;
  auto alloc = [&](size_t bytes) {
    void* p = w + off;
    off += (bytes + 255) & ~(size_t)255;
    return p;
  };
  unsigned short* Apk  = (unsigned short*)alloc((size_t)NQ * HID * 2);
  unsigned short* Bpk  = (unsigned short*)alloc((size_t)MR * HID * 2);
  unsigned short* W2bf = (unsigned short*)alloc((size_t)HID * HID * 2);
  unsigned short* Wbt  = (unsigned short*)alloc((size_t)HID * HID * 2);
  float* rowR = (float*)alloc((size_t)NQ * 4);
  float* colR = (float*)alloc((size_t)MR * 4);

  // Partial-sum slabs live in out_pi (dead until k_final rewrites it);
  // k_comb consumes them before k_final runs (stream order).
  float* rowPS = out_pi + (size_t)0 * 96 * NQ;
  float* colPS = out_pi + (size_t)1 * 96 * NQ;

  k_prep<<<dim3(HID * HID / 256), 256, 0, stream>>>(W2, Wb, W2bf, Wbt);
  k_compress<<<dim3((NQ + MR) / 16), 256, 0, stream>>>(q, r, W1, b1, W2bf, b2,
                                                       Wbt, Apk, Bpk);
  k_gemm<<<dim3(48, 24), 512, 0, stream>>>(Apk, Bpk, bb, out_lg, rowPS, colPS);
  k_comb<<<dim3((NQ + MR) / 256), 256, 0, stream>>>(
      rowPS, colPS, sq, sr, rowR, colR);
  k_final<<<dim3(NQ * 6), 256, 0, stream>>>(out_lg, rowR, colR, out_pi);
}